// Round 16
// baseline (281.136 us; speedup 1.0000x reference)
//
#include <hip/hip_runtime.h>
#include <math.h>

#define N_Q     16384
#define DDIM    512
#define M_SLOTS 2048
#define EPSN    1e-12f
#define TEMPU   1e-5f
#define KSCALE  25.4f                    // int8 scale for keys (clips at ~5 sigma)
#define QSCALE  127.0f
#define INV_S   (1.0f / (127.0f * 25.4f))
#define BCAP    32                       // bucket capacity per slot (Poisson(8): P(>32)~1e-9)
#define NROWB   4608                     // k_prep row blocks (18432 rows / 4 per block)
#define NZF     13440                    // float4s to zero (rowpack+colmax+cur+ovfc+done)

typedef unsigned int u32;
typedef unsigned long long u64;
typedef __attribute__((ext_vector_type(4))) int i32x4;

// ---------- helpers ----------
__device__ __forceinline__ void gld_lds16(const void* g, void* l) {
    __builtin_amdgcn_global_load_lds(
        (const __attribute__((address_space(1))) u32*)(g),
        (__attribute__((address_space(3))) u32*)(l), 16, 0, 0);
}
__device__ __forceinline__ float block_reduce_sum_128(float v, float* sred, int t) {
    #pragma unroll
    for (int o = 32; o > 0; o >>= 1) v += __shfl_down(v, o, 64);
    if ((t & 63) == 0) sred[t >> 6] = v;
    __syncthreads();
    return sred[0] + sred[1];
}
__device__ __forceinline__ char q8(float x, float s) {
    int v = __float2int_rn(x * s);
    v = v < -127 ? -127 : (v > 127 ? 127 : v);
    return (char)v;
}

// ---------- kernel 1: wave-per-row normalize+quantize (shfl-only) + zero-fill ----------
__global__ __launch_bounds__(256) void k_prep(const float* __restrict__ q,
                                              const float* __restrict__ keys,
                                              char* __restrict__ qi8,
                                              char* __restrict__ ki8,
                                              float4* __restrict__ zbase) {
    int b = blockIdx.x;
    int t = threadIdx.x;
    if (b < NROWB) {
        int lane = t & 63;
        int row = b * 4 + (t >> 6);          // 0..18431
        bool isq = row < N_Q;
        const float* src = isq ? q + (size_t)row * DDIM
                               : keys + (size_t)(row - N_Q) * DDIM;
        float4 v0 = ((const float4*)src)[lane];
        float4 v1 = ((const float4*)src)[lane + 64];
        float ss = v0.x * v0.x + v0.y * v0.y + v0.z * v0.z + v0.w * v0.w
                 + v1.x * v1.x + v1.y * v1.y + v1.z * v1.z + v1.w * v1.w;
        #pragma unroll
        for (int o = 32; o > 0; o >>= 1) ss += __shfl_xor(ss, o, 64);
        float s = isq ? QSCALE / fmaxf(sqrtf(ss), EPSN) : KSCALE;
        char4 o0, o1;
        o0.x = q8(v0.x, s); o0.y = q8(v0.y, s); o0.z = q8(v0.z, s); o0.w = q8(v0.w, s);
        o1.x = q8(v1.x, s); o1.y = q8(v1.y, s); o1.z = q8(v1.z, s); o1.w = q8(v1.w, s);
        char* dst = isq ? qi8 + (size_t)row * DDIM
                        : ki8 + (size_t)(row - N_Q) * DDIM;
        ((char4*)dst)[lane] = o0;
        ((char4*)dst)[lane + 64] = o1;
    } else {
        int idx = (b - NROWB) * 256 + t;
        if (idx < NZF) zbase[idx] = make_float4(0.f, 0.f, 0.f, 0.f);
    }
}

// ---------- kernel 2: i8 MFMA score GEMM (r12 core) + fused bucket-fill ----------
// 128x128 tile, BK=64 i8, 8 K-steps, 4 waves 2x2, 3 LDS buffers, depth-2
// counted vmcnt(4). NEW: per-row done-counter — the 16th j-block to finish a
// row (atomicAdd(done)==15) re-reads the final rowpack atomically and buckets
// (row, vi) for k_gather. Release: threadfence after atomicMax, before the
// done-add; acquire: threadfence after observing 15; atomic re-read (max with
// 0) avoids stale L1. Eliminates the k_fill dispatch.
__global__ __launch_bounds__(256) void k_score(const char* __restrict__ qi8,
                                               const char* __restrict__ ki8,
                                               u64* __restrict__ rowpack,
                                               u32* __restrict__ colmax,
                                               u32* __restrict__ done,
                                               u32* __restrict__ cur,
                                               u32* __restrict__ bperm,
                                               int* __restrict__ bvi,
                                               u32* __restrict__ ovf_cnt,
                                               u32* __restrict__ ovf_n,
                                               int* __restrict__ ovf_vi) {
    __shared__ char sA[3][128 * 64];
    __shared__ char sB[3][128 * 64];

    int t = threadIdx.x;
    int lane = t & 63;
    int wid = t >> 6;
    int wrow = wid >> 1;
    int wcol = wid & 1;
    int lr = lane & 15;          // frag row (A) / col (B)
    int kc = lane >> 4;          // k-chunk 0..3 (16 i8 each)

    int n0 = blockIdx.y * 128;   // query block
    int j0 = blockIdx.x * 128;   // slot block

    int srow = t >> 2;
    int scolB = (t & 3) * 16;

    const char* gA0 = qi8 + (size_t)(n0 + srow) * DDIM + scolB;
    const char* gA1 = qi8 + (size_t)(n0 + 64 + srow) * DDIM + scolB;
    const char* gB0 = ki8 + (size_t)(j0 + srow) * DDIM + scolB;
    const char* gB1 = ki8 + (size_t)(j0 + 64 + srow) * DDIM + scolB;

    i32x4 acc[4][4] = {};

#define STAGE(buf, k0)  do {                                   \
        gld_lds16(gA0 + (k0), &sA[buf][t * 16]);               \
        gld_lds16(gA1 + (k0), &sA[buf][4096 + t * 16]);        \
        gld_lds16(gB0 + (k0), &sB[buf][t * 16]);               \
        gld_lds16(gB1 + (k0), &sB[buf][4096 + t * 16]);        \
    } while (0)

    STAGE(0, 0);
    STAGE(1, 64);
    asm volatile("s_waitcnt vmcnt(4)" ::: "memory");
    __builtin_amdgcn_s_barrier();
    __builtin_amdgcn_sched_barrier(0);

    #pragma unroll
    for (int kt = 0; kt < 8; ++kt) {
        const int cb = kt % 3;
        if (kt < 6) STAGE((kt + 2) % 3, (kt + 2) * 64);

        i32x4 a[4], b[4];
        #pragma unroll
        for (int i = 0; i < 4; ++i)
            a[i] = *(const i32x4*)&sA[cb][(wrow * 64 + i * 16 + lr) * 64 + kc * 16];
        #pragma unroll
        for (int j = 0; j < 4; ++j)
            b[j] = *(const i32x4*)&sB[cb][(wcol * 64 + j * 16 + lr) * 64 + kc * 16];
        #pragma unroll
        for (int i = 0; i < 4; ++i)
            #pragma unroll
            for (int j = 0; j < 4; ++j)
                acc[i][j] = __builtin_amdgcn_mfma_i32_16x16x64_i8(a[i], b[j], acc[i][j], 0, 0, 0);

        if (kt < 6)       asm volatile("s_waitcnt vmcnt(4)" ::: "memory");
        else if (kt == 6) asm volatile("s_waitcnt vmcnt(0)" ::: "memory");
        if (kt < 7) {
            __builtin_amdgcn_s_barrier();
            __builtin_amdgcn_sched_barrier(0);
        }
    }
#undef STAGE

    // ---- fused epilogue ----
    // C/D layout: col = lane&15 (=lr), row = (lane>>4)*4 + reg (=kc*4+r)
    #pragma unroll
    for (int i = 0; i < 4; ++i) {
        #pragma unroll
        for (int r = 0; r < 4; ++r) {
            int v = acc[i][0][r];
            int c = j0 + wcol * 64 + lr;
            #pragma unroll
            for (int j = 1; j < 4; ++j) {
                int vj = acc[i][j][r];
                int cj = j0 + wcol * 64 + j * 16 + lr;
                if (vj > v) { v = vj; c = cj; }
            }
            #pragma unroll
            for (int off = 1; off < 16; off <<= 1) {
                int ov = __shfl_xor(v, off, 64);
                int oc = __shfl_xor(c, off, 64);
                if (ov > v || (ov == v && oc < c)) { v = ov; c = oc; }
            }
            if (lr == 0) {
                int grow = n0 + wrow * 64 + i * 16 + kc * 4 + r;
                u64 pk = ((u64)(u32)(v ^ 0x80000000) << 32) | (u64)(~(u32)c);
                atomicMax(rowpack + grow, pk);
            }
        }
    }
    #pragma unroll
    for (int j = 0; j < 4; ++j) {
        int m = acc[0][j][0];
        #pragma unroll
        for (int i = 0; i < 4; ++i)
            #pragma unroll
            for (int r = 0; r < 4; ++r) m = max(m, acc[i][j][r]);
        m = max(m, __shfl_xor(m, 16, 64));
        m = max(m, __shfl_xor(m, 32, 64));
        if (kc == 0) atomicMax(colmax + j0 + wcol * 64 + j * 16 + lr,
                               (u32)m ^ 0x80000000u);   // biased: zero-init == -inf
    }

    // ---- fused fill: last j-block per row buckets (row, vi) ----
    if (lr == 0) {
        __threadfence();   // release: this lane's atomicMax ops are visible
        #pragma unroll
        for (int i = 0; i < 4; ++i) {
            #pragma unroll
            for (int r = 0; r < 4; ++r) {
                int grow = n0 + wrow * 64 + i * 16 + kc * 4 + r;
                u32 d = atomicAdd(done + grow, 1u);
                if (d == 15u) {                      // all 16 j-blocks done
                    __threadfence();                 // acquire
                    u64 p = atomicMax(rowpack + grow, 0ull);   // atomic read (final)
                    int vi = (int)(((u32)(p >> 32)) ^ 0x80000000u);
                    int g  = (int)(~(u32)(p & 0xFFFFFFFFull));
                    u32 pos = atomicAdd(cur + g, 1u);
                    if (pos < BCAP) {
                        bperm[g * BCAP + pos] = (u32)grow;
                        bvi[g * BCAP + pos] = vi;
                    } else {
                        u32 o = atomicAdd(ovf_cnt, 1u);
                        ovf_n[o] = ((u32)g << 16) | (u32)grow;
                        ovf_vi[o] = vi;
                    }
                }
            }
        }
    }
}

// ---------- kernel 3: gather + weight + final normalize (fused) ----------
__global__ __launch_bounds__(128) void k_gather_final(const char* __restrict__ qi8,
                                                      const u32* __restrict__ colmax,
                                                      const u32* __restrict__ cur,
                                                      const u32* __restrict__ bperm,
                                                      const int* __restrict__ bvi,
                                                      const u32* __restrict__ ovf_cnt,
                                                      const u32* __restrict__ ovf_n,
                                                      const int* __restrict__ ovf_vi,
                                                      const float* __restrict__ keys,
                                                      float* __restrict__ out) {
    __shared__ float sred[2];
    int j = blockIdx.x;
    int t = threadIdx.x;
    int cm = (int)(colmax[j] ^ 0x80000000u);
    u32 c = cur[j];
    u32 cnt = c < BCAP ? c : BCAP;
    float ax = 0.f, ay = 0.f, az = 0.f, aw = 0.f;
    for (u32 i = 0; i < cnt; ++i) {
        u32 n = bperm[j * BCAP + i];
        float wq = expf((float)(bvi[j * BCAP + i] - cm) * INV_S) * (1.0f / 127.0f);
        char4 q4 = ((const char4*)(qi8 + (size_t)n * DDIM))[t];
        ax = fmaf(wq, (float)q4.x, ax);
        ay = fmaf(wq, (float)q4.y, ay);
        az = fmaf(wq, (float)q4.z, az);
        aw = fmaf(wq, (float)q4.w, aw);
    }
    if (c > BCAP) {                      // rare overflow path (wave-uniform)
        u32 oc = *ovf_cnt;
        for (u32 i = 0; i < oc; ++i) {
            u32 e = ovf_n[i];
            if ((e >> 16) == (u32)j) {
                u32 n = e & 0xFFFFu;
                float wq = expf((float)(ovf_vi[i] - cm) * INV_S) * (1.0f / 127.0f);
                char4 q4 = ((const char4*)(qi8 + (size_t)n * DDIM))[t];
                ax = fmaf(wq, (float)q4.x, ax);
                ay = fmaf(wq, (float)q4.y, ay);
                az = fmaf(wq, (float)q4.z, az);
                aw = fmaf(wq, (float)q4.w, aw);
            }
        }
    }
    float4 k4 = ((const float4*)(keys + (size_t)j * DDIM))[t];
    float4 v;
    v.x = fmaf(TEMPU, ax, k4.x);
    v.y = fmaf(TEMPU, ay, k4.y);
    v.z = fmaf(TEMPU, az, k4.z);
    v.w = fmaf(TEMPU, aw, k4.w);
    float ss = v.x * v.x + v.y * v.y + v.z * v.z + v.w * v.w;
    ss = block_reduce_sum_128(ss, sred, t);
    float inv = 1.0f / fmaxf(sqrtf(ss), EPSN);
    v.x *= inv; v.y *= inv; v.z *= inv; v.w *= inv;
    ((float4*)(out + (size_t)j * DDIM))[t] = v;
}

// ---------- launch ----------
extern "C" void kernel_launch(void* const* d_in, const int* in_sizes, int n_in,
                              void* d_out, int out_size, void* d_ws, size_t ws_size,
                              hipStream_t stream) {
    const float* query = (const float*)d_in[0];   // [16384, 512] f32
    const float* keys  = (const float*)d_in[1];   // [2048, 512] f32
    float* out = (float*)d_out;                   // [2048, 512] f32

    char* ws = (char*)d_ws;
    const size_t OFF_QI8   = 0;                        //  8,388,608 B
    const size_t OFF_ROW   = 8388608;                  //    131,072 B  rowpack u64[16384]
    const size_t OFF_CMAX  = OFF_ROW + 131072;         //      8,192 B  colmax u32 biased
    const size_t OFF_CUR   = OFF_CMAX + 8192;          //      8,192 B  cur u32[2048]
    const size_t OFF_OVFC  = OFF_CUR + 8192;           //      2,048 B  ovf_cnt (padded)
    const size_t OFF_DONE  = OFF_OVFC + 2048;          //     65,536 B  done u32[16384]
    const size_t OFF_BPERM = OFF_DONE + 65536;         //    262,144 B  bperm u32[2048][32]
    const size_t OFF_BVI   = OFF_BPERM + 262144;       //    262,144 B  bvi i32[2048][32]
    const size_t OFF_OVFN  = OFF_BVI + 262144;         //     65,536 B  ovf_n
    const size_t OFF_OVFVI = OFF_OVFN + 65536;         //     65,536 B  ovf_vi
    const size_t OFF_KI8   = OFF_OVFVI + 65536;        //  1,048,576 B

    char*   qi8    = ws + OFF_QI8;
    u64*    rowpack= (u64*)(ws + OFF_ROW);
    u32*    cmax   = (u32*)(ws + OFF_CMAX);
    u32*    cur    = (u32*)(ws + OFF_CUR);
    u32*    ovfc   = (u32*)(ws + OFF_OVFC);
    u32*    done   = (u32*)(ws + OFF_DONE);
    u32*    bperm  = (u32*)(ws + OFF_BPERM);
    int*    bvi    = (int*)(ws + OFF_BVI);
    u32*    ovfn   = (u32*)(ws + OFF_OVFN);
    int*    ovfvi  = (int*)(ws + OFF_OVFVI);
    char*   ki8    = ws + OFF_KI8;

    // k_prep zero-fills rowpack+colmax+cur+ovfc+done (NZF float4s, last blocks)
    k_prep<<<NROWB + (NZF + 255) / 256, 256, 0, stream>>>(query, keys, qi8, ki8,
                                                          (float4*)(ws + OFF_ROW));

    dim3 g2(M_SLOTS / 128, N_Q / 128);  // 16 x 128
    k_score<<<g2, 256, 0, stream>>>(qi8, ki8, rowpack, cmax, done, cur,
                                    bperm, bvi, ovfc, ovfn, ovfvi);

    k_gather_final<<<M_SLOTS, 128, 0, stream>>>(qi8, cmax, cur, bperm, bvi,
                                                ovfc, ovfn, ovfvi, keys, out);
}

// Round 17
// 71.084 us; speedup vs baseline: 3.9550x; 3.9550x over previous
//
#include <hip/hip_runtime.h>
#include <math.h>

#define N_Q     16384
#define DDIM    512
#define M_SLOTS 2048
#define EPSN    1e-12f
#define TEMPU   1e-5f
#define KSCALE  25.4f                    // int8 scale for keys (clips at ~5 sigma)
#define QSCALE  127.0f
#define INV_S   (1.0f / (127.0f * 25.4f))
#define BCAP    32                       // bucket capacity per slot (Poisson(8): P(>32)~1e-9)
#define NROWB   4608                     // k_prep row blocks (18432 rows / 4 per block)
#define NZF     9344                     // float4s to zero (rowpack+cmax+cur+ovfc = 149504 B)

typedef unsigned int u32;
typedef unsigned long long u64;
typedef __attribute__((ext_vector_type(4))) int i32x4;

// ---------- helpers ----------
__device__ __forceinline__ void gld_lds16(const void* g, void* l) {
    __builtin_amdgcn_global_load_lds(
        (const __attribute__((address_space(1))) u32*)(g),
        (__attribute__((address_space(3))) u32*)(l), 16, 0, 0);
}
__device__ __forceinline__ float block_reduce_sum_128(float v, float* sred, int t) {
    #pragma unroll
    for (int o = 32; o > 0; o >>= 1) v += __shfl_down(v, o, 64);
    if ((t & 63) == 0) sred[t >> 6] = v;
    __syncthreads();
    return sred[0] + sred[1];
}
__device__ __forceinline__ char q8(float x, float s) {
    int v = __float2int_rn(x * s);
    v = v < -127 ? -127 : (v > 127 ? 127 : v);
    return (char)v;
}

// ---------- kernel 1: wave-per-row normalize+quantize (shfl-only) + zero-fill ----------
// Validated in r16 (absmax fingerprint unchanged). No LDS, no __syncthreads.
__global__ __launch_bounds__(256) void k_prep(const float* __restrict__ q,
                                              const float* __restrict__ keys,
                                              char* __restrict__ qi8,
                                              char* __restrict__ ki8,
                                              float4* __restrict__ zbase) {
    int b = blockIdx.x;
    int t = threadIdx.x;
    if (b < NROWB) {
        int lane = t & 63;
        int row = b * 4 + (t >> 6);          // 0..18431
        bool isq = row < N_Q;
        const float* src = isq ? q + (size_t)row * DDIM
                               : keys + (size_t)(row - N_Q) * DDIM;
        float4 v0 = ((const float4*)src)[lane];
        float4 v1 = ((const float4*)src)[lane + 64];
        float ss = v0.x * v0.x + v0.y * v0.y + v0.z * v0.z + v0.w * v0.w
                 + v1.x * v1.x + v1.y * v1.y + v1.z * v1.z + v1.w * v1.w;
        #pragma unroll
        for (int o = 32; o > 0; o >>= 1) ss += __shfl_xor(ss, o, 64);
        float s = isq ? QSCALE / fmaxf(sqrtf(ss), EPSN) : KSCALE;
        char4 o0, o1;
        o0.x = q8(v0.x, s); o0.y = q8(v0.y, s); o0.z = q8(v0.z, s); o0.w = q8(v0.w, s);
        o1.x = q8(v1.x, s); o1.y = q8(v1.y, s); o1.z = q8(v1.z, s); o1.w = q8(v1.w, s);
        char* dst = isq ? qi8 + (size_t)row * DDIM
                        : ki8 + (size_t)(row - N_Q) * DDIM;
        ((char4*)dst)[lane] = o0;
        ((char4*)dst)[lane + 64] = o1;
    } else {
        int idx = (b - NROWB) * 256 + t;
        if (idx < NZF) zbase[idx] = make_float4(0.f, 0.f, 0.f, 0.f);
    }
}

// ---------- kernel 2: i8 MFMA score GEMM (r12/r7 config — measured optimum) ----------
// 128x128 tile, BK=64 i8, 8 K-steps, 4 waves 2x2, 3 LDS buffers, depth-2
// counted vmcnt(4) + raw s_barrier. Linear LDS (conflicts measured off the
// critical path, r11). No setprio (negative on lockstep, r11/m190). No
// threadfence anywhere (r16: −200 µs lesson).
__global__ __launch_bounds__(256) void k_score(const char* __restrict__ qi8,
                                               const char* __restrict__ ki8,
                                               u64* __restrict__ rowpack,
                                               u32* __restrict__ colmax) {
    __shared__ char sA[3][128 * 64];
    __shared__ char sB[3][128 * 64];

    int t = threadIdx.x;
    int lane = t & 63;
    int wid = t >> 6;
    int wrow = wid >> 1;
    int wcol = wid & 1;
    int lr = lane & 15;          // frag row (A) / col (B)
    int kc = lane >> 4;          // k-chunk 0..3 (16 i8 each)

    int n0 = blockIdx.y * 128;   // query block
    int j0 = blockIdx.x * 128;   // slot block

    int srow = t >> 2;
    int scolB = (t & 3) * 16;    // byte offset within 64B row

    const char* gA0 = qi8 + (size_t)(n0 + srow) * DDIM + scolB;
    const char* gA1 = qi8 + (size_t)(n0 + 64 + srow) * DDIM + scolB;
    const char* gB0 = ki8 + (size_t)(j0 + srow) * DDIM + scolB;
    const char* gB1 = ki8 + (size_t)(j0 + 64 + srow) * DDIM + scolB;

    i32x4 acc[4][4] = {};

#define STAGE(buf, k0)  do {                                   \
        gld_lds16(gA0 + (k0), &sA[buf][t * 16]);               \
        gld_lds16(gA1 + (k0), &sA[buf][4096 + t * 16]);        \
        gld_lds16(gB0 + (k0), &sB[buf][t * 16]);               \
        gld_lds16(gB1 + (k0), &sB[buf][4096 + t * 16]);        \
    } while (0)

    // prologue: 2 stages in flight; wait for the oldest (4 newest may remain)
    STAGE(0, 0);
    STAGE(1, 64);
    asm volatile("s_waitcnt vmcnt(4)" ::: "memory");
    __builtin_amdgcn_s_barrier();
    __builtin_amdgcn_sched_barrier(0);

    #pragma unroll
    for (int kt = 0; kt < 8; ++kt) {
        const int cb = kt % 3;
        if (kt < 6) STAGE((kt + 2) % 3, (kt + 2) * 64);

        i32x4 a[4], b[4];
        #pragma unroll
        for (int i = 0; i < 4; ++i)
            a[i] = *(const i32x4*)&sA[cb][(wrow * 64 + i * 16 + lr) * 64 + kc * 16];
        #pragma unroll
        for (int j = 0; j < 4; ++j)
            b[j] = *(const i32x4*)&sB[cb][(wcol * 64 + j * 16 + lr) * 64 + kc * 16];
        #pragma unroll
        for (int i = 0; i < 4; ++i)
            #pragma unroll
            for (int j = 0; j < 4; ++j)
                acc[i][j] = __builtin_amdgcn_mfma_i32_16x16x64_i8(a[i], b[j], acc[i][j], 0, 0, 0);

        // gate NEXT buffer: wait for stage kt+1; keep this iter's stage in flight
        if (kt < 6)       asm volatile("s_waitcnt vmcnt(4)" ::: "memory");
        else if (kt == 6) asm volatile("s_waitcnt vmcnt(0)" ::: "memory");
        if (kt < 7) {
            __builtin_amdgcn_s_barrier();
            __builtin_amdgcn_sched_barrier(0);
        }
    }
#undef STAGE

    // ---- fused epilogue (int scores) ----
    // C/D layout: col = lane&15 (=lr), row = (lane>>4)*4 + reg (=kc*4+r)
    #pragma unroll
    for (int i = 0; i < 4; ++i) {
        #pragma unroll
        for (int r = 0; r < 4; ++r) {
            int v = acc[i][0][r];
            int c = j0 + wcol * 64 + lr;
            #pragma unroll
            for (int j = 1; j < 4; ++j) {
                int vj = acc[i][j][r];
                int cj = j0 + wcol * 64 + j * 16 + lr;
                if (vj > v) { v = vj; c = cj; }
            }
            #pragma unroll
            for (int off = 1; off < 16; off <<= 1) {
                int ov = __shfl_xor(v, off, 64);
                int oc = __shfl_xor(c, off, 64);
                if (ov > v || (ov == v && oc < c)) { v = ov; c = oc; }
            }
            if (lr == 0) {
                int grow = n0 + wrow * 64 + i * 16 + kc * 4 + r;
                u64 pk = ((u64)(u32)(v ^ 0x80000000) << 32) | (u64)(~(u32)c);
                atomicMax(rowpack + grow, pk);
            }
        }
    }
    #pragma unroll
    for (int j = 0; j < 4; ++j) {
        int m = acc[0][j][0];
        #pragma unroll
        for (int i = 0; i < 4; ++i)
            #pragma unroll
            for (int r = 0; r < 4; ++r) m = max(m, acc[i][j][r]);
        m = max(m, __shfl_xor(m, 16, 64));
        m = max(m, __shfl_xor(m, 32, 64));
        if (kc == 0) atomicMax(colmax + j0 + wcol * 64 + j * 16 + lr,
                               (u32)m ^ 0x80000000u);   // biased: zero-init == -inf
    }
}

// ---------- kernel 3: bucket-claim fill ----------
__global__ __launch_bounds__(256) void k_fill(const u64* __restrict__ rowpack,
                                              const u32* __restrict__ colmax,
                                              u32* __restrict__ cur,
                                              u32* __restrict__ bperm,
                                              float* __restrict__ bw,
                                              u32* __restrict__ ovf_cnt,
                                              u32* __restrict__ ovf_n,
                                              float* __restrict__ ovf_w) {
    int n = blockIdx.x * 256 + threadIdx.x;
    u64 p = rowpack[n];
    int vi = (int)(((u32)(p >> 32)) ^ 0x80000000u);
    int g = (int)(~(u32)(p & 0xFFFFFFFFull));
    int cm = (int)(colmax[g] ^ 0x80000000u);
    float w = expf((float)(vi - cm) * INV_S);   // <= 1
    u32 pos = atomicAdd(cur + g, 1u);
    if (pos < BCAP) {
        bperm[g * BCAP + pos] = (u32)n;
        bw[g * BCAP + pos] = w;
    } else {
        u32 o = atomicAdd(ovf_cnt, 1u);
        ovf_n[o] = ((u32)g << 16) | (u32)n;
        ovf_w[o] = w;
    }
}

// ---------- kernel 4: gather + final normalize (fused) ----------
__global__ __launch_bounds__(128) void k_gather_final(const char* __restrict__ qi8,
                                                      const u32* __restrict__ cur,
                                                      const u32* __restrict__ bperm,
                                                      const float* __restrict__ bw,
                                                      const u32* __restrict__ ovf_cnt,
                                                      const u32* __restrict__ ovf_n,
                                                      const float* __restrict__ ovf_w,
                                                      const float* __restrict__ keys,
                                                      float* __restrict__ out) {
    __shared__ float sred[2];
    int j = blockIdx.x;
    int t = threadIdx.x;
    u32 c = cur[j];
    u32 cnt = c < BCAP ? c : BCAP;
    float ax = 0.f, ay = 0.f, az = 0.f, aw = 0.f;
    for (u32 i = 0; i < cnt; ++i) {
        u32 n = bperm[j * BCAP + i];
        float wq = bw[j * BCAP + i] * (1.0f / 127.0f);   // dequantized weight
        char4 q4 = ((const char4*)(qi8 + (size_t)n * DDIM))[t];
        ax = fmaf(wq, (float)q4.x, ax);
        ay = fmaf(wq, (float)q4.y, ay);
        az = fmaf(wq, (float)q4.z, az);
        aw = fmaf(wq, (float)q4.w, aw);
    }
    if (c > BCAP) {                      // rare overflow path (wave-uniform)
        u32 oc = *ovf_cnt;
        for (u32 i = 0; i < oc; ++i) {
            u32 e = ovf_n[i];
            if ((e >> 16) == (u32)j) {
                u32 n = e & 0xFFFFu;
                float wq = ovf_w[i] * (1.0f / 127.0f);
                char4 q4 = ((const char4*)(qi8 + (size_t)n * DDIM))[t];
                ax = fmaf(wq, (float)q4.x, ax);
                ay = fmaf(wq, (float)q4.y, ay);
                az = fmaf(wq, (float)q4.z, az);
                aw = fmaf(wq, (float)q4.w, aw);
            }
        }
    }
    float4 k4 = ((const float4*)(keys + (size_t)j * DDIM))[t];
    float4 v;
    v.x = fmaf(TEMPU, ax, k4.x);
    v.y = fmaf(TEMPU, ay, k4.y);
    v.z = fmaf(TEMPU, az, k4.z);
    v.w = fmaf(TEMPU, aw, k4.w);
    float ss = v.x * v.x + v.y * v.y + v.z * v.z + v.w * v.w;
    ss = block_reduce_sum_128(ss, sred, t);
    float inv = 1.0f / fmaxf(sqrtf(ss), EPSN);
    v.x *= inv; v.y *= inv; v.z *= inv; v.w *= inv;
    ((float4*)(out + (size_t)j * DDIM))[t] = v;
}

// ---------- launch ----------
extern "C" void kernel_launch(void* const* d_in, const int* in_sizes, int n_in,
                              void* d_out, int out_size, void* d_ws, size_t ws_size,
                              hipStream_t stream) {
    const float* query = (const float*)d_in[0];   // [16384, 512] f32
    const float* keys  = (const float*)d_in[1];   // [2048, 512] f32
    float* out = (float*)d_out;                   // [2048, 512] f32

    char* ws = (char*)d_ws;
    const size_t OFF_QI8   = 0;                        //  8,388,608 B
    const size_t OFF_ROW   = 8388608;                  //    131,072 B  rowpack u64[16384]
    const size_t OFF_CMAX  = OFF_ROW + 131072;         //      8,192 B  colmax u32 biased
    const size_t OFF_CUR   = OFF_CMAX + 8192;          //      8,192 B  cur u32[2048]
    const size_t OFF_OVFC  = OFF_CUR + 8192;           //      2,048 B  ovf_cnt (padded)
    const size_t OFF_BPERM = OFF_OVFC + 2048;          //    262,144 B  bperm u32[2048][32]
    const size_t OFF_BW    = OFF_BPERM + 262144;       //    262,144 B  bw f32[2048][32]
    const size_t OFF_OVFN  = OFF_BW + 262144;          //     65,536 B  ovf_n
    const size_t OFF_OVFW  = OFF_OVFN + 65536;         //     65,536 B  ovf_w
    const size_t OFF_KI8   = OFF_OVFW + 65536;         //  1,048,576 B

    char*   qi8    = ws + OFF_QI8;
    u64*    rowpack= (u64*)(ws + OFF_ROW);
    u32*    cmax   = (u32*)(ws + OFF_CMAX);
    u32*    cur    = (u32*)(ws + OFF_CUR);
    u32*    ovfc   = (u32*)(ws + OFF_OVFC);
    u32*    bperm  = (u32*)(ws + OFF_BPERM);
    float*  bw     = (float*)(ws + OFF_BW);
    u32*    ovfn   = (u32*)(ws + OFF_OVFN);
    float*  ovfw   = (float*)(ws + OFF_OVFW);
    char*   ki8    = ws + OFF_KI8;

    // k_prep zero-fills rowpack+colmax+cur+ovf_cnt (last blocks, NZF float4s)
    k_prep<<<NROWB + (NZF + 255) / 256, 256, 0, stream>>>(query, keys, qi8, ki8,
                                                          (float4*)(ws + OFF_ROW));

    dim3 g2(M_SLOTS / 128, N_Q / 128);  // 16 x 128
    k_score<<<g2, 256, 0, stream>>>(qi8, ki8, rowpack, cmax);

    k_fill<<<N_Q / 256, 256, 0, stream>>>(rowpack, cmax, cur, bperm, bw,
                                          ovfc, ovfn, ovfw);
    k_gather_final<<<M_SLOTS, 128, 0, stream>>>(qi8, cur, bperm, bw,
                                                ovfc, ovfn, ovfw, keys, out);
}